// Round 2
// baseline (142.047 us; speedup 1.0000x reference)
//
#include <hip/hip_runtime.h>
#include <hip/hip_bf16.h>

// RewardCLIP loss:
//   diff[i] = dot(input_embs[i] - neg_input_embs[i], image_embs[i])
//   loss = -mean(log_sigmoid(diff * alpha))
//
// Memory-bound: 3 x 65536 x 1024 x 4B = 768 MiB read.
// R1 change vs R0: explicit 12-load batch per row (forces 12 outstanding
// global_load_dwordx4 per wave -> MLP), 4 independent accumulators,
// blocked consecutive-row assignment per wave (32KB sequential streams).

#define DIMS 1024
#define BLOCKS 2048
#define THREADS 256
#define WAVES_PER_BLOCK (THREADS / 64)
#define ROWS_PER_WAVE 8   // 2048 blocks * 4 waves * 8 rows = 65536

__global__ __launch_bounds__(THREADS) void rewardclip_main(
    const float* __restrict__ a,      // input_embs
    const float* __restrict__ b,      // neg_input_embs
    const float* __restrict__ c,      // image_embs
    const int* __restrict__ alpha_p,  // scalar (python int)
    int rows,
    float* __restrict__ partials) {
  const int tid  = threadIdx.x;
  const int lane = tid & 63;
  const int wave = tid >> 6;
  const int gwave = blockIdx.x * WAVES_PER_BLOCK + wave;

  const float alpha = (float)(*alpha_p);

  float acc = 0.0f;  // lane-0-valid accumulator of log_sigmoid values

  const int row0 = gwave * ROWS_PER_WAVE;
#pragma unroll 1
  for (int r = 0; r < ROWS_PER_WAVE; ++r) {
    const int row = row0 + r;
    if (row >= rows) break;
    const float4* __restrict__ pa = (const float4*)(a + (size_t)row * DIMS) + lane;
    const float4* __restrict__ pb = (const float4*)(b + (size_t)row * DIMS) + lane;
    const float4* __restrict__ pc = (const float4*)(c + (size_t)row * DIMS) + lane;

    // Issue all 12 loads before any arithmetic: 12 outstanding dwordx4/wave.
    const float4 a0 = pa[0], a1 = pa[64], a2 = pa[128], a3 = pa[192];
    const float4 b0 = pb[0], b1 = pb[64], b2 = pb[128], b3 = pb[192];
    const float4 c0 = pc[0], c1 = pc[64], c2 = pc[128], c3 = pc[192];

    float d0 = 0.f, d1 = 0.f, d2 = 0.f, d3 = 0.f;
    d0 += (a0.x - b0.x) * c0.x; d0 += (a0.y - b0.y) * c0.y;
    d0 += (a0.z - b0.z) * c0.z; d0 += (a0.w - b0.w) * c0.w;
    d1 += (a1.x - b1.x) * c1.x; d1 += (a1.y - b1.y) * c1.y;
    d1 += (a1.z - b1.z) * c1.z; d1 += (a1.w - b1.w) * c1.w;
    d2 += (a2.x - b2.x) * c2.x; d2 += (a2.y - b2.y) * c2.y;
    d2 += (a2.z - b2.z) * c2.z; d2 += (a2.w - b2.w) * c2.w;
    d3 += (a3.x - b3.x) * c3.x; d3 += (a3.y - b3.y) * c3.y;
    d3 += (a3.z - b3.z) * c3.z; d3 += (a3.w - b3.w) * c3.w;

    float d = (d0 + d1) + (d2 + d3);

    // 64-lane shuffle reduction
#pragma unroll
    for (int off = 32; off > 0; off >>= 1) d += __shfl_down(d, off, 64);

    if (lane == 0) {
      const float x = d * alpha;
      const float ls = fminf(x, 0.0f) - log1pf(__expf(-fabsf(x)));
      acc += ls;
    }
  }

  __shared__ float s[WAVES_PER_BLOCK];
  if (lane == 0) s[wave] = acc;
  __syncthreads();
  if (tid == 0) {
    float t = 0.0f;
#pragma unroll
    for (int w = 0; w < WAVES_PER_BLOCK; ++w) t += s[w];
    partials[blockIdx.x] = t;  // fully overwritten every launch: deterministic
  }
}

__global__ __launch_bounds__(THREADS) void rewardclip_finalize(
    const float* __restrict__ partials, int nparts, int rows,
    float* __restrict__ out) {
  const int tid  = threadIdx.x;
  const int lane = tid & 63;
  const int wave = tid >> 6;

  float s = 0.0f;
  for (int i = tid; i < nparts; i += THREADS) s += partials[i];

#pragma unroll
  for (int off = 32; off > 0; off >>= 1) s += __shfl_down(s, off, 64);

  __shared__ float ws[WAVES_PER_BLOCK];
  if (lane == 0) ws[wave] = s;
  __syncthreads();
  if (tid == 0) {
    float t = 0.0f;
#pragma unroll
    for (int w = 0; w < WAVES_PER_BLOCK; ++w) t += ws[w];
    out[0] = -t / (float)rows;
  }
}

extern "C" void kernel_launch(void* const* d_in, const int* in_sizes, int n_in,
                              void* d_out, int out_size, void* d_ws, size_t ws_size,
                              hipStream_t stream) {
  const float* a = (const float*)d_in[0];       // input_embs
  const float* b = (const float*)d_in[1];       // neg_input_embs
  const float* c = (const float*)d_in[2];       // image_embs
  const int* alpha_p = (const int*)d_in[3];     // python int scalar

  const int rows = in_sizes[0] / DIMS;          // 65536
  float* partials = (float*)d_ws;               // BLOCKS floats
  float* out = (float*)d_out;

  rewardclip_main<<<BLOCKS, THREADS, 0, stream>>>(a, b, c, alpha_p, rows, partials);
  rewardclip_finalize<<<1, THREADS, 0, stream>>>(partials, BLOCKS, rows, out);
}